// Round 3
// baseline (397.729 us; speedup 1.0000x reference)
//
#include <hip/hip_runtime.h>

#define B 8
#define P 2048
#define C 1024
#define NCHUNK 32
#define FEAT4 (B*P*C/4)   // 4194304 float4s of features
#define CEN4  (B*P*3/4)   // 12288 float4s of centers (and of cls_preds)

typedef unsigned long long u64;
typedef unsigned int u32;

__device__ __forceinline__ u64 shfl_xor_u64(u64 x, int m) {
    int lo = __shfl_xor((int)(u32)x, m, 64);
    int hi = __shfl_xor((int)(u32)(x >> 32), m, 64);
    return ((u64)(u32)hi << 32) | (u32)lo;
}
__device__ __forceinline__ u64 shfl_u64(u64 x, int s) {
    int lo = __shfl((int)(u32)x, s, 64);
    int hi = __shfl((int)(u32)(x >> 32), s, 64);
    return ((u64)(u32)hi << 32) | (u32)lo;
}

// ---------------------------------------------------------------------------
// K1: per-scene sort on packed 64-bit keys. Hybrid bitonic: j>=64 via LDS
// (15 barriered passes), j<=32 via shfl_xor in registers (51 barrier-free
// passes). Key = (~ord(score) << 32) | (idx<<2) | label, ascending sort =>
// descending score, ties -> smaller idx (greedy argmax tie semantics).
// Epilogue gathers sorted centers (xyz + label bits) and sorted idx.
// ---------------------------------------------------------------------------
__global__ __launch_bounds__(1024) void sort_kernel(
    const float* __restrict__ centers,
    const float* __restrict__ cls_preds,
    float4* __restrict__ scent,
    int* __restrict__ sidx)
{
    __shared__ u64 s_k[P];
    const int b = blockIdx.x, tid = threadIdx.x;
    const float* clsb = cls_preds + (size_t)b * P * 3;
    const float* cenb = centers + (size_t)b * P * 3;

    u64 v[2];
    #pragma unroll
    for (int h = 0; h < 2; ++h) {
        int e = tid + h * 1024;
        float s0 = clsb[e*3], s1 = clsb[e*3+1], s2 = clsb[e*3+2];
        float sc = s0; int lb = 0;
        if (s1 > sc) { sc = s1; lb = 1; }
        if (s2 > sc) { sc = s2; lb = 2; }
        u32 ub = __float_as_uint(sc);
        u32 ord = (ub & 0x80000000u) ? ~ub : (ub | 0x80000000u); // ascending map
        u32 dsc = ~ord;                                          // descending
        v[h] = ((u64)dsc << 32) | (u32)((e << 2) | lb);
    }

    for (int k = 2; k <= P; k <<= 1) {
        for (int j = k >> 1; j >= 64; j >>= 1) {     // LDS passes
            s_k[tid] = v[0]; s_k[tid + 1024] = v[1];
            __syncthreads();
            #pragma unroll
            for (int h = 0; h < 2; ++h) {
                int e = tid + h * 1024;
                u64 p = s_k[e ^ j];
                bool asc = (e & k) == 0;
                bool upper = (e & j) != 0;
                u64 mn = v[h] < p ? v[h] : p;
                u64 mx = v[h] < p ? p : v[h];
                v[h] = (asc != upper) ? mn : mx;
            }
            __syncthreads();
        }
        int jtop = (k >> 1) < 32 ? (k >> 1) : 32;
        for (int j = jtop; j >= 1; j >>= 1) {        // shfl passes, no barrier
            #pragma unroll
            for (int h = 0; h < 2; ++h) {
                int e = tid + h * 1024;
                u64 p = shfl_xor_u64(v[h], j);
                bool asc = (e & k) == 0;
                bool upper = (e & j) != 0;
                u64 mn = v[h] < p ? v[h] : p;
                u64 mx = v[h] < p ? p : v[h];
                v[h] = (asc != upper) ? mn : mx;
            }
        }
    }

    s_k[tid] = v[0]; s_k[tid + 1024] = v[1];
    __syncthreads();
    #pragma unroll
    for (int h = 0; h < 2; ++h) {
        int pos = tid + h * 1024;
        u32 lo = (u32)s_k[pos];
        int orig = (int)(lo >> 2);
        float4 c;
        c.x = cenb[orig*3]; c.y = cenb[orig*3+1]; c.z = cenb[orig*3+2];
        c.w = __int_as_float((int)(lo & 3));
        scent[b * P + pos] = c;
        sidx[b * P + pos] = (int)lo;
    }
}

// ---------------------------------------------------------------------------
// K2: suppression bit-matrix in sorted order, full GPU (8 scenes x 32 chunks
// = 256 blocks x 4 waves). Block (b,g): lane j = g*64+lane tests vs all
// earlier i. Cross-chunk bits -> mat[b][w][j] (word-major: coalesced for K3).
// Within-chunk (symmetric) -> diag col mask (bits strictly above own lane).
// Waves split the i-tiles; no barriers (broadcast global loads, L1-served).
// ---------------------------------------------------------------------------
__global__ __launch_bounds__(256) void matrix_kernel(
    const float4* __restrict__ scent,
    const float* __restrict__ class_radius,
    u32* __restrict__ mat,
    u64* __restrict__ diag)
{
    const int b = blockIdx.x >> 5, g = blockIdx.x & 31;
    const int wv = threadIdx.x >> 6, lane = threadIdx.x & 63;
    const int base = g << 6, iend = base + 64;
    const float4 cj = scent[b * P + base + lane];
    const int labj = __float_as_int(cj.w);
    const float r = class_radius[labj];
    const float r2 = r * r;
    const int ntile = (iend + 255) >> 8;

    u64 sym = 0;
    for (int t = wv; t < ntile; t += 4) {
        const int tb = t << 8;
        const int tlim = min(256, iend - tb);
        u32 wacc = 0;
        for (int u = 0; u < tlim; ++u) {
            const int i = tb + u;
            const float4 ci = scent[b * P + i];       // broadcast, L1
            bool sup = false;
            if (__float_as_int(ci.w) == labj) {
                float dx = cj.x - ci.x, dy = cj.y - ci.y, dz = cj.z - ci.z;
                sup = (dx*dx + dy*dy + dz*dz) < r2;
            }
            if (i < base) {
                wacc |= ((u32)sup) << (i & 31);
                if ((i & 31) == 31) {
                    mat[((size_t)b * 64 + (i >> 5)) * P + base + lane] = wacc;
                    wacc = 0;
                }
            } else {
                if (sup && i != base + lane) sym |= 1ull << (i - base);
            }
        }
    }
    // owner wave of the last tile (contains [base,iend)) writes diag
    if (wv == ((ntile - 1) & 3)) {
        u64 col = (lane == 63) ? 0ull : (sym & (~0ull << (lane + 1)));
        diag[((size_t)b * 32 + g) * 64 + lane] = col;
    }
}

// ---------------------------------------------------------------------------
// K3: greedy resolution, one wave per scene, ZERO barriers. Per chunk:
// removed = OR_w (mat column & kept word) -> ballot; then ffs-driven scan
// (iterations = #kept in chunk) with shfl-broadcast diagonal columns.
// Scatters keep floats by original index.
// ---------------------------------------------------------------------------
__global__ __launch_bounds__(64) void scan_kernel(
    const u32* __restrict__ mat,
    const u64* __restrict__ diag,
    const int* __restrict__ sidx,
    float* __restrict__ out_keep)
{
    __shared__ u32 s_kept[64];
    const int b = blockIdx.x, lane = threadIdx.x;

    for (int g = 0; g < NCHUNK; ++g) {
        const int base = g << 6;
        const int j = base + lane;
        const int W = 2 * g;
        u32 acc = 0;
        int w = 0;
        for (; w + 4 <= W; w += 4) {
            u32 m0 = mat[((size_t)b*64 + w  ) * P + j];
            u32 m1 = mat[((size_t)b*64 + w+1) * P + j];
            u32 m2 = mat[((size_t)b*64 + w+2) * P + j];
            u32 m3 = mat[((size_t)b*64 + w+3) * P + j];
            acc |= (m0 & s_kept[w]) | (m1 & s_kept[w+1])
                 | (m2 & s_kept[w+2]) | (m3 & s_kept[w+3]);
        }
        for (; w < W; ++w) acc |= mat[((size_t)b*64 + w) * P + j] & s_kept[w];

        u64 rem = __ballot(acc != 0);
        u64 col = diag[((size_t)b * 32 + g) * 64 + lane];
        u64 todo = ~rem;
        u64 keepmask = 0;
        while (todo) {                               // wave-uniform
            int k = (int)__ffsll((long long)todo) - 1;
            keepmask |= 1ull << k;
            u64 ck = shfl_u64(col, k);
            todo &= ~ck;
            todo &= ~(1ull << k);
        }
        if (lane < 2) s_kept[2*g + lane] = (u32)(keepmask >> (32 * lane));
        const int si = sidx[b * P + j];
        const int orig = si >> 2;
        out_keep[b * P + orig] = ((keepmask >> lane) & 1ull) ? 1.0f : 0.0f;
    }
}

// ---------------------------------------------------------------------------
// K4: streaming mask of all outputs (features + centers + cls), full GPU.
// ---------------------------------------------------------------------------
__global__ __launch_bounds__(256) void mask_kernel(
    const float* __restrict__ centers,
    const float* __restrict__ features,
    const float* __restrict__ cls_preds,
    const float* __restrict__ keep,
    float* __restrict__ out_centers,
    float* __restrict__ out_feat,
    float* __restrict__ out_cls)
{
    const int idx = blockIdx.x * 256 + threadIdx.x;
    if (idx < FEAT4) {
        const int row = idx >> 8;                    // C/4 = 256 f4 per row
        const float m = keep[row];
        float4 v = ((const float4*)features)[idx];
        v.x *= m; v.y *= m; v.z *= m; v.w *= m;
        ((float4*)out_feat)[idx] = v;
    } else if (idx < FEAT4 + CEN4) {
        const int q = idx - FEAT4;
        float4 v = ((const float4*)centers)[q];
        const int e = q * 4;
        v.x *= keep[(e    ) / 3]; v.y *= keep[(e + 1) / 3];
        v.z *= keep[(e + 2) / 3]; v.w *= keep[(e + 3) / 3];
        ((float4*)out_centers)[q] = v;
    } else if (idx < FEAT4 + 2 * CEN4) {
        const int q = idx - FEAT4 - CEN4;
        float4 v = ((const float4*)cls_preds)[q];
        const int e = q * 4;
        v.x *= keep[(e    ) / 3]; v.y *= keep[(e + 1) / 3];
        v.z *= keep[(e + 2) / 3]; v.w *= keep[(e + 3) / 3];
        ((float4*)out_cls)[q] = v;
    }
}

extern "C" void kernel_launch(void* const* d_in, const int* in_sizes, int n_in,
                              void* d_out, int out_size, void* d_ws, size_t ws_size,
                              hipStream_t stream) {
    const float* centers      = (const float*)d_in[0];
    const float* features     = (const float*)d_in[1];
    const float* cls_preds    = (const float*)d_in[2];
    const float* class_radius = (const float*)d_in[3];

    float* out = (float*)d_out;
    float* out_centers = out;                                   // B*P*3
    float* out_feat    = out + (size_t)B * P * 3;               // B*P*C
    float* out_cls     = out_feat + (size_t)B * P * C;          // B*P*K
    float* out_keep    = out_cls + (size_t)B * P * 3;           // B*P

    // scratch lives inside out_feat (64 MB), fully rewritten by mask_kernel:
    //   mat   : 1,048,576 u32   (4 MB)   mat[b][w][j]
    //   scent :    16,384 float4
    //   sidx  :    16,384 int
    //   diag  :    16,384 u64
    u32*    mat   = (u32*)out_feat;
    float4* scent = (float4*)(out_feat + 1048576);
    int*    sidx  = (int*)(out_feat + 1048576 + 65536);
    u64*    diag  = (u64*)(out_feat + 1048576 + 65536 + 16384);

    hipLaunchKernelGGL(sort_kernel, dim3(B), dim3(1024), 0, stream,
                       centers, cls_preds, scent, sidx);
    hipLaunchKernelGGL(matrix_kernel, dim3(B * 32), dim3(256), 0, stream,
                       scent, class_radius, mat, diag);
    hipLaunchKernelGGL(scan_kernel, dim3(B), dim3(64), 0, stream,
                       mat, diag, sidx, out_keep);
    hipLaunchKernelGGL(mask_kernel, dim3((FEAT4 + 2 * CEN4 + 255) / 256), dim3(256),
                       0, stream,
                       centers, features, cls_preds, out_keep,
                       out_centers, out_feat, out_cls);
}

// Round 4
// 259.177 us; speedup vs baseline: 1.5346x; 1.5346x over previous
//
#include <hip/hip_runtime.h>

#define B 8
#define P 2048
#define C 1024
#define NCHUNK 32
#define FEAT4 (B*P*C/4)   // 4194304 float4s of features
#define CEN4  (B*P*3/4)   // 12288 float4s of centers (and of cls_preds)

typedef unsigned long long u64;
typedef unsigned int u32;

__device__ __forceinline__ u64 shfl_xor_u64(u64 x, int m) {
    int lo = __shfl_xor((int)(u32)x, m, 64);
    int hi = __shfl_xor((int)(u32)(x >> 32), m, 64);
    return ((u64)(u32)hi << 32) | (u32)lo;
}
__device__ __forceinline__ u64 shfl_u64(u64 x, int s) {
    int lo = __shfl((int)(u32)x, s, 64);
    int hi = __shfl((int)(u32)(x >> 32), s, 64);
    return ((u64)(u32)hi << 32) | (u32)lo;
}

// ---------------------------------------------------------------------------
// K1: per-scene sort on packed 64-bit keys. Hybrid bitonic: j>=64 via LDS,
// j<=32 via shfl_xor (barrier-free). Key = (desc score) << 32 | idx<<2 | lab.
// ---------------------------------------------------------------------------
__global__ __launch_bounds__(1024) void sort_kernel(
    const float* __restrict__ centers,
    const float* __restrict__ cls_preds,
    float4* __restrict__ scent,
    int* __restrict__ sidx)
{
    __shared__ u64 s_k[P];
    const int b = blockIdx.x, tid = threadIdx.x;
    const float* clsb = cls_preds + (size_t)b * P * 3;
    const float* cenb = centers + (size_t)b * P * 3;

    u64 v[2];
    #pragma unroll
    for (int h = 0; h < 2; ++h) {
        int e = tid + h * 1024;
        float s0 = clsb[e*3], s1 = clsb[e*3+1], s2 = clsb[e*3+2];
        float sc = s0; int lb = 0;
        if (s1 > sc) { sc = s1; lb = 1; }
        if (s2 > sc) { sc = s2; lb = 2; }
        u32 ub = __float_as_uint(sc);
        u32 ord = (ub & 0x80000000u) ? ~ub : (ub | 0x80000000u); // ascending map
        u32 dsc = ~ord;                                          // descending
        v[h] = ((u64)dsc << 32) | (u32)((e << 2) | lb);
    }

    for (int k = 2; k <= P; k <<= 1) {
        for (int j = k >> 1; j >= 64; j >>= 1) {     // LDS passes
            s_k[tid] = v[0]; s_k[tid + 1024] = v[1];
            __syncthreads();
            #pragma unroll
            for (int h = 0; h < 2; ++h) {
                int e = tid + h * 1024;
                u64 p = s_k[e ^ j];
                bool asc = (e & k) == 0;
                bool upper = (e & j) != 0;
                u64 mn = v[h] < p ? v[h] : p;
                u64 mx = v[h] < p ? p : v[h];
                v[h] = (asc != upper) ? mn : mx;
            }
            __syncthreads();
        }
        int jtop = (k >> 1) < 32 ? (k >> 1) : 32;
        for (int j = jtop; j >= 1; j >>= 1) {        // shfl passes, no barrier
            #pragma unroll
            for (int h = 0; h < 2; ++h) {
                int e = tid + h * 1024;
                u64 p = shfl_xor_u64(v[h], j);
                bool asc = (e & k) == 0;
                bool upper = (e & j) != 0;
                u64 mn = v[h] < p ? v[h] : p;
                u64 mx = v[h] < p ? p : v[h];
                v[h] = (asc != upper) ? mn : mx;
            }
        }
    }

    s_k[tid] = v[0]; s_k[tid + 1024] = v[1];
    __syncthreads();
    #pragma unroll
    for (int h = 0; h < 2; ++h) {
        int pos = tid + h * 1024;
        u32 lo = (u32)s_k[pos];
        int orig = (int)(lo >> 2);
        float4 c;
        c.x = cenb[orig*3]; c.y = cenb[orig*3+1]; c.z = cenb[orig*3+2];
        c.w = __int_as_float((int)(lo & 3));
        scent[b * P + pos] = c;
        sidx[b * P + pos] = (int)lo;
    }
}

// ---------------------------------------------------------------------------
// K2: suppression bit-matrix, LDS-tiled. Block (b,g): lane j = g*64+lane
// tests vs all i < 64*(g+1). Tiles of 256 i staged cooperatively into LDS
// (coalesced float4), inner loop reads LDS broadcast (free) -- no dependent
// global loads. Wave wv owns i-subrange [tb+64*wv, tb+64*wv+64): writes its
// own 2 mat words per tile; the wave whose subrange == [base,iend) writes
// the diagonal column masks. mat layout: mat[b][g][w][lane] (contiguous
// 16 KB per (b,g)) so K3 reads one coalesced burst per chunk.
// ---------------------------------------------------------------------------
__global__ __launch_bounds__(256) void matrix_kernel(
    const float4* __restrict__ scent,
    const float* __restrict__ class_radius,
    u32* __restrict__ mat,
    u64* __restrict__ diag)
{
    __shared__ float4 s_t[256];
    const int b = blockIdx.x >> 5, g = blockIdx.x & 31;
    const int wv = threadIdx.x >> 6, lane = threadIdx.x & 63;
    const int base = g << 6, iend = base + 64;
    const float4 cj = scent[(size_t)b * P + base + lane];
    const int labj = __float_as_int(cj.w);
    const float r = class_radius[labj];
    const float r2 = r * r;
    u32* mc = mat + ((size_t)b * 32 + g) * 64 * 64;

    for (int tb = 0; tb < iend; tb += 256) {
        int si = tb + threadIdx.x;
        if (si < P) s_t[threadIdx.x] = scent[(size_t)b * P + si];
        __syncthreads();
        const int i0 = tb + (wv << 6);
        if (i0 < base) {                     // cross-chunk words
            u32 w0 = 0, w1 = 0;
            #pragma unroll
            for (int u = 0; u < 64; ++u) {
                float4 ci = s_t[(wv << 6) + u];       // LDS broadcast
                bool sup = false;
                if (__float_as_int(ci.w) == labj) {
                    float dx = cj.x-ci.x, dy = cj.y-ci.y, dz = cj.z-ci.z;
                    sup = (dx*dx + dy*dy + dz*dz) < r2;
                }
                if (u < 32) w0 |= ((u32)sup) << u;
                else        w1 |= ((u32)sup) << (u - 32);
            }
            const int w = i0 >> 5;
            mc[(w    ) * 64 + lane] = w0;
            mc[(w + 1) * 64 + lane] = w1;
        } else if (i0 == base) {             // diagonal 64x64 block
            u64 sym = 0;
            #pragma unroll
            for (int u = 0; u < 64; ++u) {
                float4 ci = s_t[(wv << 6) + u];
                if (u != lane && __float_as_int(ci.w) == labj) {
                    float dx = cj.x-ci.x, dy = cj.y-ci.y, dz = cj.z-ci.z;
                    if (dx*dx + dy*dy + dz*dz < r2) sym |= 1ull << u;
                }
            }
            // suppression is symmetric (same class => same radius), so row
            // mask == column mask; keep only indices strictly after lane.
            u64 col = (lane == 63) ? 0ull : (sym & (~0ull << (lane + 1)));
            diag[((size_t)b * 32 + g) * 64 + lane] = col;
        }
        __syncthreads();
    }
}

// ---------------------------------------------------------------------------
// K3: greedy resolution, one block (8 waves) per scene. Per chunk: the 8
// waves split the <=62 kept-word AND/OR columns (coalesced contiguous reads
// of this chunk's 16 KB mat slab, <=8 independent loads/lane -> one memory
// round-trip), LDS-reduce, wave 0 resolves via ballot/ffs scan with
// LDS-preloaded diagonal columns. 2 barriers/chunk.
// ---------------------------------------------------------------------------
__global__ __launch_bounds__(512) void scan_kernel(
    const u32* __restrict__ mat,
    const u64* __restrict__ diag,
    const int* __restrict__ sidx,
    float* __restrict__ out_keep)
{
    __shared__ u64 s_diag[NCHUNK * 64];
    __shared__ u32 s_acc[8][64];
    __shared__ u32 s_kept[64];
    __shared__ unsigned char s_keepb[P];
    const int b = blockIdx.x;
    const int tid = threadIdx.x, wave = tid >> 6, lane = tid & 63;

    #pragma unroll
    for (int rr = 0; rr < 4; ++rr)
        s_diag[tid + 512 * rr] = diag[(size_t)b * 2048 + tid + 512 * rr];
    if (tid < 64) s_kept[tid] = 0;
    __syncthreads();

    const u32* matb = mat + (size_t)b * 32 * 64 * 64;
    for (int g = 0; g < NCHUNK; ++g) {
        const int W = 2 * g;
        const u32* mc = matb + g * 64 * 64;
        u32 acc = 0;
        #pragma unroll
        for (int rr = 0; rr < 8; ++rr) {
            int w = wave + 8 * rr;
            if (w < W) acc |= mc[w * 64 + lane] & s_kept[w];
        }
        s_acc[wave][lane] = acc;
        __syncthreads();
        if (wave == 0) {
            u32 a = 0;
            #pragma unroll
            for (int w2 = 0; w2 < 8; ++w2) a |= s_acc[w2][lane];
            u64 rem = __ballot(a != 0);
            u64 col = s_diag[g * 64 + lane];
            u64 todo = ~rem;
            u64 keepmask = 0;
            while (todo) {                           // wave-uniform
                int k = (int)__ffsll((long long)todo) - 1;
                keepmask |= 1ull << k;
                u64 ck = shfl_u64(col, k);
                todo &= ~ck & ~(1ull << k);
            }
            s_keepb[(g << 6) + lane] = (unsigned char)((keepmask >> lane) & 1ull);
            if (lane < 2) s_kept[W + lane] = (u32)(keepmask >> (32 * lane));
        }
        __syncthreads();
    }

    for (int pos = tid; pos < P; pos += 512) {
        int orig = sidx[(size_t)b * P + pos] >> 2;
        out_keep[(size_t)b * P + orig] = s_keepb[pos] ? 1.0f : 0.0f;
    }
}

// ---------------------------------------------------------------------------
// K4: streaming mask of all outputs (features + centers + cls), full GPU.
// ---------------------------------------------------------------------------
__global__ __launch_bounds__(256) void mask_kernel(
    const float* __restrict__ centers,
    const float* __restrict__ features,
    const float* __restrict__ cls_preds,
    const float* __restrict__ keep,
    float* __restrict__ out_centers,
    float* __restrict__ out_feat,
    float* __restrict__ out_cls)
{
    const int idx = blockIdx.x * 256 + threadIdx.x;
    if (idx < FEAT4) {
        const int row = idx >> 8;                    // C/4 = 256 f4 per row
        const float m = keep[row];
        float4 v = ((const float4*)features)[idx];
        v.x *= m; v.y *= m; v.z *= m; v.w *= m;
        ((float4*)out_feat)[idx] = v;
    } else if (idx < FEAT4 + CEN4) {
        const int q = idx - FEAT4;
        float4 v = ((const float4*)centers)[q];
        const int e = q * 4;
        v.x *= keep[(e    ) / 3]; v.y *= keep[(e + 1) / 3];
        v.z *= keep[(e + 2) / 3]; v.w *= keep[(e + 3) / 3];
        ((float4*)out_centers)[q] = v;
    } else if (idx < FEAT4 + 2 * CEN4) {
        const int q = idx - FEAT4 - CEN4;
        float4 v = ((const float4*)cls_preds)[q];
        const int e = q * 4;
        v.x *= keep[(e    ) / 3]; v.y *= keep[(e + 1) / 3];
        v.z *= keep[(e + 2) / 3]; v.w *= keep[(e + 3) / 3];
        ((float4*)out_cls)[q] = v;
    }
}

extern "C" void kernel_launch(void* const* d_in, const int* in_sizes, int n_in,
                              void* d_out, int out_size, void* d_ws, size_t ws_size,
                              hipStream_t stream) {
    const float* centers      = (const float*)d_in[0];
    const float* features     = (const float*)d_in[1];
    const float* cls_preds    = (const float*)d_in[2];
    const float* class_radius = (const float*)d_in[3];

    float* out = (float*)d_out;
    float* out_centers = out;                                   // B*P*3
    float* out_feat    = out + (size_t)B * P * 3;               // B*P*C
    float* out_cls     = out_feat + (size_t)B * P * C;          // B*P*K
    float* out_keep    = out_cls + (size_t)B * P * 3;           // B*P

    // scratch inside out_feat (64 MB), fully rewritten by mask_kernel:
    //   mat   : 1,048,576 u32 (4 MB), layout mat[b][g][w][lane]
    //   scent :    16,384 float4
    //   sidx  :    16,384 int
    //   diag  :    16,384 u64
    u32*    mat   = (u32*)out_feat;
    float4* scent = (float4*)(out_feat + 1048576);
    int*    sidx  = (int*)(out_feat + 1048576 + 65536);
    u64*    diag  = (u64*)(out_feat + 1048576 + 65536 + 16384);

    hipLaunchKernelGGL(sort_kernel, dim3(B), dim3(1024), 0, stream,
                       centers, cls_preds, scent, sidx);
    hipLaunchKernelGGL(matrix_kernel, dim3(B * 32), dim3(256), 0, stream,
                       scent, class_radius, mat, diag);
    hipLaunchKernelGGL(scan_kernel, dim3(B), dim3(512), 0, stream,
                       mat, diag, sidx, out_keep);
    hipLaunchKernelGGL(mask_kernel, dim3((FEAT4 + 2 * CEN4 + 255) / 256), dim3(256),
                       0, stream,
                       centers, features, cls_preds, out_keep,
                       out_centers, out_feat, out_cls);
}